// Round 3
// baseline (23071.320 us; speedup 1.0000x reference)
//
#include <hip/hip_runtime.h>

#define NT 512   // timesteps
#define FB 128   // feature bins
#define HD 256   // L1 == L2 hidden
#define NC 10

typedef __attribute__((ext_vector_type(8))) short bf16x8;
typedef __attribute__((ext_vector_type(4))) float f32x4;

static __device__ __forceinline__ short f2bf(float f){
  union { float f; unsigned u; } v; v.f = f;
  return (short)((v.u + 0x7fffu + ((v.u >> 16) & 1u)) >> 16);  // RNE
}
static __device__ __forceinline__ float bf2f(short h){
  union { unsigned u; float f; } v; v.u = ((unsigned)(unsigned short)h) << 16;
  return v.f;
}
static __device__ __forceinline__ float quantw(float w){
  return fminf(fmaxf(rintf(w * 8.0f) * 0.125f, -1.0f), 1.0f);  // 4-bit fixed point, exact in bf16
}
static __device__ __forceinline__ bf16x8 loadqw8(const float* __restrict__ p){
  bf16x8 v;
#pragma unroll
  for (int j = 0; j < 8; ++j) v[j] = f2bf(quantw(p[j]));
  return v;
}
// split 8 floats into hi bf16 + lo bf16 (residual)
static __device__ __forceinline__ void split8(f32x4 a, f32x4 b, bf16x8& hi, bf16x8& lo){
  float v0[4] = {a[0],a[1],a[2],a[3]}, v1[4] = {b[0],b[1],b[2],b[3]};
#pragma unroll
  for (int j = 0; j < 4; ++j){
    short h = f2bf(v0[j]); hi[j] = h; lo[j] = f2bf(v0[j] - bf2f(h));
  }
#pragma unroll
  for (int j = 0; j < 4; ++j){
    short h = f2bf(v1[j]); hi[4+j] = h; lo[4+j] = f2bf(v1[j] - bf2f(h));
  }
}

// Persistent kernel, plain launch (256 blocks = 1/CU; co-resident by construction).
// 256 blocks: group gp = bid&31 (8 batch rows), slice sb = bid>>5 (32 h-dims of W1/W2).
// Flags region of d_ws is zeroed by hipMemsetAsync on the same stream before launch,
// so no grid-wide sync is needed anywhere.
// in1/in2 LDS rows 0..7 = hi(batch row), rows 8..15 = lo(batch row) -> split-bf16 activations.
__global__ __launch_bounds__(256, 1)
void egru_persistent(const float* __restrict__ xg,
                     const float* __restrict__ h1ig, const float* __restrict__ h2ig,
                     const float* __restrict__ W1g, const float* __restrict__ b1g,
                     const float* __restrict__ W2g, const float* __restrict__ b2g,
                     const float* __restrict__ W3g, const float* __restrict__ b3g,
                     const float* __restrict__ W4g, const float* __restrict__ b4g,
                     float* __restrict__ outg, float* __restrict__ wsf)
{
  const int tid = threadIdx.x;
  const int sb  = blockIdx.x >> 5;   // slice 0..7
  const int gp  = blockIdx.x & 31;   // group 0..31
  const int wv  = tid >> 6;          // wave 0..3
  const int ln  = tid & 15;          // MFMA frag: m/n index (lane&15)
  const int lk  = (tid >> 4) & 3;    // MFMA frag: k-subgroup (lane>>4)
  const int rz  = sb * 32;           // this slice's h-dim base
  const int lnl = 8 + (ln & 7);      // row for lo-part B reads (valid cols 0..7 only)

  __shared__ __align__(16) short in1[16*384];   // [row][k]: k<128 = x(t), k>=128 = h1; rows 0-7 hi, 8-15 lo
  __shared__ __align__(16) short in2[16*512];   // k<256 = h1(t), k>=256 = h2; rows 0-7 hi, 8-15 lo
  __shared__ float a_lds[64][17];
  __shared__ float h1own[32][8];                // fp32 master of own slice [j][r]
  __shared__ float h2own[32][8];
  __shared__ float h3row[128];
  __shared__ float W4L[10*130];
  __shared__ float b1s[64], b2s[64], b3L[128], b4L[10];

  // workspace: h1buf[32][8][256] f32, h2buf[32][8][256] f32, flags[32][32] u32 (pre-zeroed)
  float* h1buf = wsf + (size_t)gp * (8*HD);
  float* h2buf = wsf + (size_t)32*8*HD + (size_t)gp * (8*HD);
  unsigned* flags = reinterpret_cast<unsigned*>(wsf + (size_t)2*32*8*HD) + gp * 32;

  // ---- resident weight fragments (A-operand: lane holds A[m=ln][k=lk*8+j (+32*ks)]) ----
  // quantized weights are multiples of 1/8 in [-1,1] -> EXACT in bf16 (no split needed)
  bf16x8 w1f[12], w2f[16], w3f[2][8];
  {
    const int arow = (wv < 2) ? (rz + wv*16 + ln) : (256 + rz + (wv-2)*16 + ln);
#pragma unroll
    for (int ks = 0; ks < 12; ++ks) w1f[ks] = loadqw8(W1g + arow*384 + ks*32 + lk*8);
#pragma unroll
    for (int ks = 0; ks < 16; ++ks) w2f[ks] = loadqw8(W2g + arow*512 + ks*32 + lk*8);
#pragma unroll
    for (int tl = 0; tl < 2; ++tl)
#pragma unroll
      for (int ks = 0; ks < 8; ++ks)
        w3f[tl][ks] = loadqw8(W3g + (wv*32 + tl*16 + ln)*256 + ks*32 + lk*8);
  }

  if (tid < 64){
    int grow = (tid < 32) ? (rz + tid) : (256 + rz + (tid - 32));
    b1s[tid] = b1g[grow];
    b2s[tid] = b2g[grow];
  }
  if (tid < 128) b3L[tid] = b3g[tid];
  if (tid < 10)  b4L[tid] = b4g[tid];
  for (int i = tid; i < 1280; i += 256)
    W4L[(i >> 7)*130 + (i & 127)] = quantw(W4g[i]);

  const int ur = tid >> 5, uc = tid & 31;   // (batch row, 8-chunk) mapping, 8x32
  {
    bf16x8 hv, lv;
    const float* p1 = h1ig + (size_t)(gp*8 + ur)*HD + uc*8;
    split8(*(const f32x4*)p1, *(const f32x4*)(p1+4), hv, lv);
    *(bf16x8*)((char*)in1 + ur*768       + ((256 + uc*16) ^ ((ur&7)<<4))) = hv;
    *(bf16x8*)((char*)in1 + (ur+8)*768   + ((256 + uc*16) ^ ((ur&7)<<4))) = lv;
    *(bf16x8*)((char*)in2 + ur*1024      + ((      uc*16) ^ ((ur&7)<<4))) = hv;
    *(bf16x8*)((char*)in2 + (ur+8)*1024  + ((      uc*16) ^ ((ur&7)<<4))) = lv;
    const float* p2 = h2ig + (size_t)(gp*8 + ur)*HD + uc*8;
    split8(*(const f32x4*)p2, *(const f32x4*)(p2+4), hv, lv);
    *(bf16x8*)((char*)in2 + ur*1024      + ((512 + uc*16) ^ ((ur&7)<<4))) = hv;
    *(bf16x8*)((char*)in2 + (ur+8)*1024  + ((512 + uc*16) ^ ((ur&7)<<4))) = lv;
    h1own[uc][ur] = h1ig[(size_t)(gp*8+ur)*HD + rz + uc];
    h2own[uc][ur] = h2ig[(size_t)(gp*8+ur)*HD + rz + uc];
  }
  const int xr = tid >> 4, xf = tid & 15;   // x-staging mapping (rows >=8 unused)
  if (xr < 8){
    const float* px = xg + ((size_t)(gp*8 + xr)*NT + 0)*FB + xf*8;
    bf16x8 hv, lv;
    split8(*(const f32x4*)px, *(const f32x4*)(px+4), hv, lv);
    *(bf16x8*)((char*)in1 + xr*768     + ((xf*16) ^ ((xr&7)<<4))) = hv;
    *(bf16x8*)((char*)in1 + (xr+8)*768 + ((xf*16) ^ ((xr&7)<<4))) = lv;
  }
  __syncthreads();

  for (int t = 0; t < NT; ++t){
    // prefetch x(t+1) into regs (consumed mid-iteration)
    f32x4 xa = {0,0,0,0}, xb = {0,0,0,0};
    const bool pf = ((t+1) < NT) && (xr < 8);
    if (pf){
      const float* px = xg + ((size_t)(gp*8 + xr)*NT + (t+1))*FB + xf*8;
      xa = *(const f32x4*)px; xb = *(const f32x4*)(px+4);
    }

    // ---- L1: a1-slice [16m x 8n], K=384, hi+lo ----
    f32x4 acc = {0.f,0.f,0.f,0.f};
#pragma unroll
    for (int ks = 0; ks < 12; ++ks){
      bf16x8 bhi = *(bf16x8*)((char*)in1 + ln*768  + ((ks*64 + lk*16) ^ ((ln&7)<<4)));
      bf16x8 blo = *(bf16x8*)((char*)in1 + lnl*768 + ((ks*64 + lk*16) ^ ((ln&7)<<4)));
      acc = __builtin_amdgcn_mfma_f32_16x16x32_bf16(w1f[ks], bhi, acc, 0, 0, 0);
      acc = __builtin_amdgcn_mfma_f32_16x16x32_bf16(w1f[ks], blo, acc, 0, 0, 0);
    }
#pragma unroll
    for (int r4 = 0; r4 < 4; ++r4){
      int jsl = wv*16 + lk*4 + r4;            // C/D: row=(lane>>4)*4+reg, col=lane&15
      a_lds[jsl][ln] = acc[r4] + b1s[jsl];
    }
    __syncthreads();
    { // gate update for own slice (fp32 master state)
      float az = a_lds[uc][ur], ac = a_lds[32+uc][ur];
      float z  = 0.5f*(az/(1.0f+fabsf(az)) + 1.0f);
      float cd = ac/(1.0f+fabsf(ac));
      float hn = z*h1own[uc][ur] + (1.0f - z)*cd;
      h1own[uc][ur] = hn;
      h1buf[ur*HD + rz + uc] = hn;
    }
    if (pf){  // stage x(t+1); L1 reads of x(t) completed before the barrier above
      bf16x8 hv, lv;
      split8(xa, xb, hv, lv);
      *(bf16x8*)((char*)in1 + xr*768     + ((xf*16) ^ ((xr&7)<<4))) = hv;
      *(bf16x8*)((char*)in1 + (xr+8)*768 + ((xf*16) ^ ((xr&7)<<4))) = lv;
    }

    __builtin_amdgcn_fence(__ATOMIC_RELEASE, "agent");
    __syncthreads();
    if (tid == 0) __hip_atomic_store(&flags[sb], (unsigned)(t+1), __ATOMIC_RELEASE, __HIP_MEMORY_SCOPE_AGENT);
    if (tid < 8)
      while (__hip_atomic_load(&flags[tid], __ATOMIC_ACQUIRE, __HIP_MEMORY_SCOPE_AGENT) < (unsigned)(t+1)) {}
    __syncthreads();
    __builtin_amdgcn_fence(__ATOMIC_ACQUIRE, "agent");
    { // read full h1(t) -> split bf16 into in1 (k>=128) and in2 (k<256)
      const float* ph = h1buf + ur*HD + uc*8;
      bf16x8 hv, lv;
      split8(*(const f32x4*)ph, *(const f32x4*)(ph+4), hv, lv);
      *(bf16x8*)((char*)in1 + ur*768      + ((256 + uc*16) ^ ((ur&7)<<4))) = hv;
      *(bf16x8*)((char*)in1 + (ur+8)*768  + ((256 + uc*16) ^ ((ur&7)<<4))) = lv;
      *(bf16x8*)((char*)in2 + ur*1024     + ((      uc*16) ^ ((ur&7)<<4))) = hv;
      *(bf16x8*)((char*)in2 + (ur+8)*1024 + ((      uc*16) ^ ((ur&7)<<4))) = lv;
    }
    __syncthreads();

    // ---- L2: K=512 over [h1(t), h2(t-1)], hi+lo ----
    f32x4 acc2 = {0.f,0.f,0.f,0.f};
#pragma unroll
    for (int ks = 0; ks < 16; ++ks){
      bf16x8 bhi = *(bf16x8*)((char*)in2 + ln*1024  + ((ks*64 + lk*16) ^ ((ln&7)<<4)));
      bf16x8 blo = *(bf16x8*)((char*)in2 + lnl*1024 + ((ks*64 + lk*16) ^ ((ln&7)<<4)));
      acc2 = __builtin_amdgcn_mfma_f32_16x16x32_bf16(w2f[ks], bhi, acc2, 0, 0, 0);
      acc2 = __builtin_amdgcn_mfma_f32_16x16x32_bf16(w2f[ks], blo, acc2, 0, 0, 0);
    }
#pragma unroll
    for (int r4 = 0; r4 < 4; ++r4){
      int jsl = wv*16 + lk*4 + r4;
      a_lds[jsl][ln] = acc2[r4] + b2s[jsl];
    }
    __syncthreads();
    {
      float az = a_lds[uc][ur], ac = a_lds[32+uc][ur];
      float z  = 0.5f*(az/(1.0f+fabsf(az)) + 1.0f);
      float cd = ac/(1.0f+fabsf(ac));
      float hn = z*h2own[uc][ur] + (1.0f - z)*cd;
      h2own[uc][ur] = hn;
      h2buf[ur*HD + rz + uc] = hn;
    }
    __builtin_amdgcn_fence(__ATOMIC_RELEASE, "agent");
    __syncthreads();
    if (tid == 0) __hip_atomic_store(&flags[8 + sb], (unsigned)(t+1), __ATOMIC_RELEASE, __HIP_MEMORY_SCOPE_AGENT);
    if (tid < 8)
      while (__hip_atomic_load(&flags[8 + tid], __ATOMIC_ACQUIRE, __HIP_MEMORY_SCOPE_AGENT) < (unsigned)(t+1)) {}
    __syncthreads();
    __builtin_amdgcn_fence(__ATOMIC_ACQUIRE, "agent");
    { // read full h2(t) -> in2 (k>=256); also serves L2 of step t+1
      const float* ph = h2buf + ur*HD + uc*8;
      bf16x8 hv, lv;
      split8(*(const f32x4*)ph, *(const f32x4*)(ph+4), hv, lv);
      *(bf16x8*)((char*)in2 + ur*1024     + ((512 + uc*16) ^ ((ur&7)<<4))) = hv;
      *(bf16x8*)((char*)in2 + (ur+8)*1024 + ((512 + uc*16) ^ ((ur&7)<<4))) = lv;
    }
    __syncthreads();

    // ---- L3 (redundant per block; W3 frags resident), keep only batch-col == sb ----
    f32x4 acc3a = {0,0,0,0}, acc3b = {0,0,0,0};
#pragma unroll
    for (int ks = 0; ks < 8; ++ks){
      bf16x8 bhi = *(bf16x8*)((char*)in2 + ln*1024  + ((512 + ks*64 + lk*16) ^ ((ln&7)<<4)));
      bf16x8 blo = *(bf16x8*)((char*)in2 + lnl*1024 + ((512 + ks*64 + lk*16) ^ ((ln&7)<<4)));
      acc3a = __builtin_amdgcn_mfma_f32_16x16x32_bf16(w3f[0][ks], bhi, acc3a, 0, 0, 0);
      acc3a = __builtin_amdgcn_mfma_f32_16x16x32_bf16(w3f[0][ks], blo, acc3a, 0, 0, 0);
      acc3b = __builtin_amdgcn_mfma_f32_16x16x32_bf16(w3f[1][ks], bhi, acc3b, 0, 0, 0);
      acc3b = __builtin_amdgcn_mfma_f32_16x16x32_bf16(w3f[1][ks], blo, acc3b, 0, 0, 0);
    }
    if (ln == sb){
#pragma unroll
      for (int r4 = 0; r4 < 4; ++r4){
        int d0 = wv*32 + lk*4 + r4;
        h3row[d0]      = fmaxf(acc3a[r4] + b3L[d0],      0.0f);
        h3row[d0 + 16] = fmaxf(acc3b[r4] + b3L[d0 + 16], 0.0f);
      }
    }
    __syncthreads();

    // ---- L4 + log_softmax for this block's batch row (wave 0 only) ----
    if (wv == 0){
      const int lc = tid;   // lane id within wave 0
      float y = -INFINITY;
      if (lc < 10){
        y = b4L[lc];
#pragma unroll 8
        for (int k = 0; k < 128; ++k)
          y += W4L[lc*130 + k] * h3row[k];
      }
      float mx = y;
#pragma unroll
      for (int off = 1; off < 16; off <<= 1)
        mx = fmaxf(mx, __shfl_xor(mx, off, 16));
      float ex = (lc < 10) ? expf(y - mx) : 0.0f;
      float sm = ex;
#pragma unroll
      for (int off = 1; off < 16; off <<= 1)
        sm += __shfl_xor(sm, off, 16);
      float lse = mx + logf(sm);
      if (lc < 10)
        outg[((size_t)(gp*8 + sb)*NT + t)*NC + lc] = y - lse;
    }
    // no barrier needed: wave0 rejoins at the L1-epilogue barrier of step t+1;
    // h3row is next written only after that barrier chain
  }
}

extern "C" void kernel_launch(void* const* d_in, const int* in_sizes, int n_in,
                              void* d_out, int out_size, void* d_ws, size_t ws_size,
                              hipStream_t stream) {
  const float* xg  = (const float*)d_in[0];
  const float* h1i = (const float*)d_in[1];
  const float* h2i = (const float*)d_in[2];
  const float* W1  = (const float*)d_in[3];
  const float* b1  = (const float*)d_in[4];
  const float* W2  = (const float*)d_in[5];
  const float* b2  = (const float*)d_in[6];
  const float* W3  = (const float*)d_in[7];
  const float* b3  = (const float*)d_in[8];
  const float* W4  = (const float*)d_in[9];
  const float* b4  = (const float*)d_in[10];
  float* out = (float*)d_out;
  float* ws  = (float*)d_ws;

  // zero the flag words (stream-ordered, so it completes before the kernel starts)
  const size_t flags_off = (size_t)2 * 32 * 8 * HD * sizeof(float);  // 512 KiB
  hipMemsetAsync((char*)d_ws + flags_off, 0, 32 * 32 * sizeof(unsigned), stream);

  egru_persistent<<<dim3(256), dim3(256), 0, stream>>>(
      xg, h1i, h2i, W1, b1, W2, b2, W3, b3, W4, b4, out, ws);
}

// Round 4
// 3875.055 us; speedup vs baseline: 5.9538x; 5.9538x over previous
//
#include <hip/hip_runtime.h>

#define NT 512   // timesteps
#define FB 128   // feature bins
#define HD 256   // L1 == L2 hidden
#define NC 10

typedef __attribute__((ext_vector_type(8))) short bf16x8;
typedef __attribute__((ext_vector_type(4))) float f32x4;

static __device__ __forceinline__ short f2bf(float f){
  union { float f; unsigned u; } v; v.f = f;
  return (short)((v.u + 0x7fffu + ((v.u >> 16) & 1u)) >> 16);  // RNE
}
static __device__ __forceinline__ float bf2f(short h){
  union { unsigned u; float f; } v; v.u = ((unsigned)(unsigned short)h) << 16;
  return v.f;
}
static __device__ __forceinline__ float quantw(float w){
  return fminf(fmaxf(rintf(w * 8.0f) * 0.125f, -1.0f), 1.0f);  // 4-bit fixed point, exact in bf16
}
static __device__ __forceinline__ bf16x8 loadqw8(const float* __restrict__ p){
  bf16x8 v;
#pragma unroll
  for (int j = 0; j < 8; ++j) v[j] = f2bf(quantw(p[j]));
  return v;
}
// split 8 floats into hi bf16 + lo bf16 (residual)
static __device__ __forceinline__ void split8(f32x4 a, f32x4 b, bf16x8& hi, bf16x8& lo){
  float v0[4] = {a[0],a[1],a[2],a[3]}, v1[4] = {b[0],b[1],b[2],b[3]};
#pragma unroll
  for (int j = 0; j < 4; ++j){
    short h = f2bf(v0[j]); hi[j] = h; lo[j] = f2bf(v0[j] - bf2f(h));
  }
#pragma unroll
  for (int j = 0; j < 4; ++j){
    short h = f2bf(v1[j]); hi[4+j] = h; lo[4+j] = f2bf(v1[j] - bf2f(h));
  }
}

// system-scope relaxed (sc0 sc1) accessors: bypass L1/L2, hit the coherent point,
// NO buffer_wbl2 / buffer_inv cache maintenance (that was the 45 us/step killer).
static __device__ __forceinline__ void st_sys(float* p, float v){
  __hip_atomic_store(p, v, __ATOMIC_RELAXED, __HIP_MEMORY_SCOPE_SYSTEM);
}
static __device__ __forceinline__ float ld_sys(const float* p){
  return __hip_atomic_load(p, __ATOMIC_RELAXED, __HIP_MEMORY_SCOPE_SYSTEM);
}
static __device__ __forceinline__ void st_sysu(unsigned* p, unsigned v){
  __hip_atomic_store(p, v, __ATOMIC_RELAXED, __HIP_MEMORY_SCOPE_SYSTEM);
}
static __device__ __forceinline__ unsigned ld_sysu(const unsigned* p){
  return __hip_atomic_load(p, __ATOMIC_RELAXED, __HIP_MEMORY_SCOPE_SYSTEM);
}

// Persistent kernel, plain launch (256 blocks = 1/CU; co-resident by construction).
// 256 blocks: group gp = bid&31 (8 batch rows), slice sb = bid>>5 (32 h-dims of W1/W2).
// Flags region of d_ws zeroed by hipMemsetAsync on the stream before launch.
// in1/in2 LDS rows 0..7 = hi(batch row), rows 8..15 = lo(batch row) -> split-bf16 activations.
__global__ __launch_bounds__(256, 1)
void egru_persistent(const float* __restrict__ xg,
                     const float* __restrict__ h1ig, const float* __restrict__ h2ig,
                     const float* __restrict__ W1g, const float* __restrict__ b1g,
                     const float* __restrict__ W2g, const float* __restrict__ b2g,
                     const float* __restrict__ W3g, const float* __restrict__ b3g,
                     const float* __restrict__ W4g, const float* __restrict__ b4g,
                     float* __restrict__ outg, float* __restrict__ wsf)
{
  const int tid = threadIdx.x;
  const int sb  = blockIdx.x >> 5;   // slice 0..7
  const int gp  = blockIdx.x & 31;   // group 0..31
  const int wv  = tid >> 6;          // wave 0..3
  const int ln  = tid & 15;          // MFMA frag: m/n index (lane&15)
  const int lk  = (tid >> 4) & 3;    // MFMA frag: k-subgroup (lane>>4)
  const int rz  = sb * 32;           // this slice's h-dim base
  const int lnl = 8 + (ln & 7);      // row for lo-part B reads

  __shared__ __align__(16) short in1[16*384];   // [row][k]: k<128 = x(t), k>=128 = h1; rows 0-7 hi, 8-15 lo
  __shared__ __align__(16) short in2[16*512];   // k<256 = h1(t), k>=256 = h2; rows 0-7 hi, 8-15 lo
  __shared__ float a_lds[64][17];
  __shared__ float h1own[32][8];                // fp32 master of own slice [j][r]
  __shared__ float h2own[32][8];
  __shared__ float h3row[128];
  __shared__ float W4L[10*130];
  __shared__ float b1s[64], b2s[64], b3L[128], b4L[10];

  // workspace: h1buf[32][8][256] f32, h2buf[32][8][256] f32, flags[32][32] u32 (pre-zeroed)
  float* h1buf = wsf + (size_t)gp * (8*HD);
  float* h2buf = wsf + (size_t)32*8*HD + (size_t)gp * (8*HD);
  unsigned* flags = reinterpret_cast<unsigned*>(wsf + (size_t)2*32*8*HD) + gp * 32;

  // ---- resident weight fragments (A-operand: lane holds A[m=ln][k=lk*8+j (+32*ks)]) ----
  // quantized weights are multiples of 1/8 in [-1,1] -> EXACT in bf16 (no split needed)
  bf16x8 w1f[12], w2f[16], w3f[2][8];
  {
    const int arow = (wv < 2) ? (rz + wv*16 + ln) : (256 + rz + (wv-2)*16 + ln);
#pragma unroll
    for (int ks = 0; ks < 12; ++ks) w1f[ks] = loadqw8(W1g + arow*384 + ks*32 + lk*8);
#pragma unroll
    for (int ks = 0; ks < 16; ++ks) w2f[ks] = loadqw8(W2g + arow*512 + ks*32 + lk*8);
#pragma unroll
    for (int tl = 0; tl < 2; ++tl)
#pragma unroll
      for (int ks = 0; ks < 8; ++ks)
        w3f[tl][ks] = loadqw8(W3g + (wv*32 + tl*16 + ln)*256 + ks*32 + lk*8);
  }

  if (tid < 64){
    int grow = (tid < 32) ? (rz + tid) : (256 + rz + (tid - 32));
    b1s[tid] = b1g[grow];
    b2s[tid] = b2g[grow];
  }
  if (tid < 128) b3L[tid] = b3g[tid];
  if (tid < 10)  b4L[tid] = b4g[tid];
  for (int i = tid; i < 1280; i += 256)
    W4L[(i >> 7)*130 + (i & 127)] = quantw(W4g[i]);

  const int ur = tid >> 5, uc = tid & 31;   // (batch row, 8-chunk) mapping, 8x32
  {
    bf16x8 hv, lv;
    const float* p1 = h1ig + (size_t)(gp*8 + ur)*HD + uc*8;
    split8(*(const f32x4*)p1, *(const f32x4*)(p1+4), hv, lv);
    *(bf16x8*)((char*)in1 + ur*768       + ((256 + uc*16) ^ ((ur&7)<<4))) = hv;
    *(bf16x8*)((char*)in1 + (ur+8)*768   + ((256 + uc*16) ^ ((ur&7)<<4))) = lv;
    *(bf16x8*)((char*)in2 + ur*1024      + ((      uc*16) ^ ((ur&7)<<4))) = hv;
    *(bf16x8*)((char*)in2 + (ur+8)*1024  + ((      uc*16) ^ ((ur&7)<<4))) = lv;
    const float* p2 = h2ig + (size_t)(gp*8 + ur)*HD + uc*8;
    split8(*(const f32x4*)p2, *(const f32x4*)(p2+4), hv, lv);
    *(bf16x8*)((char*)in2 + ur*1024      + ((512 + uc*16) ^ ((ur&7)<<4))) = hv;
    *(bf16x8*)((char*)in2 + (ur+8)*1024  + ((512 + uc*16) ^ ((ur&7)<<4))) = lv;
    h1own[uc][ur] = h1ig[(size_t)(gp*8+ur)*HD + rz + uc];
    h2own[uc][ur] = h2ig[(size_t)(gp*8+ur)*HD + rz + uc];
  }
  const int xr = tid >> 4, xf = tid & 15;   // x-staging mapping (rows >=8 unused)
  if (xr < 8){
    const float* px = xg + ((size_t)(gp*8 + xr)*NT + 0)*FB + xf*8;
    bf16x8 hv, lv;
    split8(*(const f32x4*)px, *(const f32x4*)(px+4), hv, lv);
    *(bf16x8*)((char*)in1 + xr*768     + ((xf*16) ^ ((xr&7)<<4))) = hv;
    *(bf16x8*)((char*)in1 + (xr+8)*768 + ((xf*16) ^ ((xr&7)<<4))) = lv;
  }
  __syncthreads();

  for (int t = 0; t < NT; ++t){
    // prefetch x(t+1) into regs (consumed mid-iteration)
    f32x4 xa = {0,0,0,0}, xb = {0,0,0,0};
    const bool pf = ((t+1) < NT) && (xr < 8);
    if (pf){
      const float* px = xg + ((size_t)(gp*8 + xr)*NT + (t+1))*FB + xf*8;
      xa = *(const f32x4*)px; xb = *(const f32x4*)(px+4);
    }

    // ---- L1: a1-slice [16m x 8n], K=384, hi+lo ----
    f32x4 acc = {0.f,0.f,0.f,0.f};
#pragma unroll
    for (int ks = 0; ks < 12; ++ks){
      bf16x8 bhi = *(bf16x8*)((char*)in1 + ln*768  + ((ks*64 + lk*16) ^ ((ln&7)<<4)));
      bf16x8 blo = *(bf16x8*)((char*)in1 + lnl*768 + ((ks*64 + lk*16) ^ ((ln&7)<<4)));
      acc = __builtin_amdgcn_mfma_f32_16x16x32_bf16(w1f[ks], bhi, acc, 0, 0, 0);
      acc = __builtin_amdgcn_mfma_f32_16x16x32_bf16(w1f[ks], blo, acc, 0, 0, 0);
    }
#pragma unroll
    for (int r4 = 0; r4 < 4; ++r4){
      int jsl = wv*16 + lk*4 + r4;            // C/D: row=(lane>>4)*4+reg, col=lane&15
      a_lds[jsl][ln] = acc[r4] + b1s[jsl];
    }
    __syncthreads();
    { // gate update for own slice (fp32 master state); publish via sc0sc1 store
      float az = a_lds[uc][ur], ac = a_lds[32+uc][ur];
      float z  = 0.5f*(az/(1.0f+fabsf(az)) + 1.0f);
      float cd = ac/(1.0f+fabsf(ac));
      float hn = z*h1own[uc][ur] + (1.0f - z)*cd;
      h1own[uc][ur] = hn;
      st_sys(&h1buf[ur*HD + rz + uc], hn);
    }
    asm volatile("s_waitcnt vmcnt(0)" ::: "memory");  // own data stores complete
    __syncthreads();                                   // whole block's stores complete
    if (tid == 0) st_sysu(&flags[sb], (unsigned)(t+1));
    if (pf){  // stage x(t+1) during the spin window; L1 reads of x(t) done pre-barrier
      bf16x8 hv, lv;
      split8(xa, xb, hv, lv);
      *(bf16x8*)((char*)in1 + xr*768     + ((xf*16) ^ ((xr&7)<<4))) = hv;
      *(bf16x8*)((char*)in1 + (xr+8)*768 + ((xf*16) ^ ((xr&7)<<4))) = lv;
    }
    if (tid < 8)
      while (ld_sysu(&flags[tid]) < (unsigned)(t+1)) {}
    __syncthreads();
    { // read full h1(t) (sc0sc1 loads, coherent) -> split bf16 into in1 (k>=128) and in2 (k<256)
      float vb[8];
      const int base = ur*HD + uc*8;
#pragma unroll
      for (int j = 0; j < 8; ++j) vb[j] = ld_sys(&h1buf[base + j]);
      f32x4 a0 = {vb[0],vb[1],vb[2],vb[3]}, a1 = {vb[4],vb[5],vb[6],vb[7]};
      bf16x8 hv, lv;
      split8(a0, a1, hv, lv);
      *(bf16x8*)((char*)in1 + ur*768      + ((256 + uc*16) ^ ((ur&7)<<4))) = hv;
      *(bf16x8*)((char*)in1 + (ur+8)*768  + ((256 + uc*16) ^ ((ur&7)<<4))) = lv;
      *(bf16x8*)((char*)in2 + ur*1024     + ((      uc*16) ^ ((ur&7)<<4))) = hv;
      *(bf16x8*)((char*)in2 + (ur+8)*1024 + ((      uc*16) ^ ((ur&7)<<4))) = lv;
    }
    __syncthreads();

    // ---- L2: K=512 over [h1(t), h2(t-1)], hi+lo ----
    f32x4 acc2 = {0.f,0.f,0.f,0.f};
#pragma unroll
    for (int ks = 0; ks < 16; ++ks){
      bf16x8 bhi = *(bf16x8*)((char*)in2 + ln*1024  + ((ks*64 + lk*16) ^ ((ln&7)<<4)));
      bf16x8 blo = *(bf16x8*)((char*)in2 + lnl*1024 + ((ks*64 + lk*16) ^ ((ln&7)<<4)));
      acc2 = __builtin_amdgcn_mfma_f32_16x16x32_bf16(w2f[ks], bhi, acc2, 0, 0, 0);
      acc2 = __builtin_amdgcn_mfma_f32_16x16x32_bf16(w2f[ks], blo, acc2, 0, 0, 0);
    }
#pragma unroll
    for (int r4 = 0; r4 < 4; ++r4){
      int jsl = wv*16 + lk*4 + r4;
      a_lds[jsl][ln] = acc2[r4] + b2s[jsl];
    }
    __syncthreads();
    {
      float az = a_lds[uc][ur], ac = a_lds[32+uc][ur];
      float z  = 0.5f*(az/(1.0f+fabsf(az)) + 1.0f);
      float cd = ac/(1.0f+fabsf(ac));
      float hn = z*h2own[uc][ur] + (1.0f - z)*cd;
      h2own[uc][ur] = hn;
      st_sys(&h2buf[ur*HD + rz + uc], hn);
    }
    asm volatile("s_waitcnt vmcnt(0)" ::: "memory");
    __syncthreads();
    if (tid == 0) st_sysu(&flags[8 + sb], (unsigned)(t+1));
    if (tid < 8)
      while (ld_sysu(&flags[8 + tid]) < (unsigned)(t+1)) {}
    __syncthreads();
    { // read full h2(t) -> in2 (k>=256); also serves L2 of step t+1
      float vb[8];
      const int base = ur*HD + uc*8;
#pragma unroll
      for (int j = 0; j < 8; ++j) vb[j] = ld_sys(&h2buf[base + j]);
      f32x4 a0 = {vb[0],vb[1],vb[2],vb[3]}, a1 = {vb[4],vb[5],vb[6],vb[7]};
      bf16x8 hv, lv;
      split8(a0, a1, hv, lv);
      *(bf16x8*)((char*)in2 + ur*1024     + ((512 + uc*16) ^ ((ur&7)<<4))) = hv;
      *(bf16x8*)((char*)in2 + (ur+8)*1024 + ((512 + uc*16) ^ ((ur&7)<<4))) = lv;
    }
    __syncthreads();

    // ---- L3 (redundant per block; W3 frags resident), keep only batch-col == sb ----
    f32x4 acc3a = {0,0,0,0}, acc3b = {0,0,0,0};
#pragma unroll
    for (int ks = 0; ks < 8; ++ks){
      bf16x8 bhi = *(bf16x8*)((char*)in2 + ln*1024  + ((512 + ks*64 + lk*16) ^ ((ln&7)<<4)));
      bf16x8 blo = *(bf16x8*)((char*)in2 + lnl*1024 + ((512 + ks*64 + lk*16) ^ ((ln&7)<<4)));
      acc3a = __builtin_amdgcn_mfma_f32_16x16x32_bf16(w3f[0][ks], bhi, acc3a, 0, 0, 0);
      acc3a = __builtin_amdgcn_mfma_f32_16x16x32_bf16(w3f[0][ks], blo, acc3a, 0, 0, 0);
      acc3b = __builtin_amdgcn_mfma_f32_16x16x32_bf16(w3f[1][ks], bhi, acc3b, 0, 0, 0);
      acc3b = __builtin_amdgcn_mfma_f32_16x16x32_bf16(w3f[1][ks], blo, acc3b, 0, 0, 0);
    }
    if (ln == sb){
#pragma unroll
      for (int r4 = 0; r4 < 4; ++r4){
        int d0 = wv*32 + lk*4 + r4;
        h3row[d0]      = fmaxf(acc3a[r4] + b3L[d0],      0.0f);
        h3row[d0 + 16] = fmaxf(acc3b[r4] + b3L[d0 + 16], 0.0f);
      }
    }
    __syncthreads();

    // ---- L4 + log_softmax for this block's batch row (wave 0 only) ----
    if (wv == 0){
      const int lc = tid;   // lane id within wave 0
      float y = -INFINITY;
      if (lc < 10){
        y = b4L[lc];
#pragma unroll 8
        for (int k = 0; k < 128; ++k)
          y += W4L[lc*130 + k] * h3row[k];
      }
      float mx = y;
#pragma unroll
      for (int off = 1; off < 16; off <<= 1)
        mx = fmaxf(mx, __shfl_xor(mx, off, 16));
      float ex = (lc < 10) ? expf(y - mx) : 0.0f;
      float sm = ex;
#pragma unroll
      for (int off = 1; off < 16; off <<= 1)
        sm += __shfl_xor(sm, off, 16);
      float lse = mx + logf(sm);
      if (lc < 10)
        outg[((size_t)(gp*8 + sb)*NT + t)*NC + lc] = y - lse;
    }
    // no barrier needed: wave0 rejoins at the L1-epilogue barrier of step t+1;
    // h3row is next written only after that barrier chain
  }
}

extern "C" void kernel_launch(void* const* d_in, const int* in_sizes, int n_in,
                              void* d_out, int out_size, void* d_ws, size_t ws_size,
                              hipStream_t stream) {
  const float* xg  = (const float*)d_in[0];
  const float* h1i = (const float*)d_in[1];
  const float* h2i = (const float*)d_in[2];
  const float* W1  = (const float*)d_in[3];
  const float* b1  = (const float*)d_in[4];
  const float* W2  = (const float*)d_in[5];
  const float* b2  = (const float*)d_in[6];
  const float* W3  = (const float*)d_in[7];
  const float* b3  = (const float*)d_in[8];
  const float* W4  = (const float*)d_in[9];
  const float* b4  = (const float*)d_in[10];
  float* out = (float*)d_out;
  float* ws  = (float*)d_ws;

  // zero the flag words (stream-ordered, completes before the kernel starts)
  const size_t flags_off = (size_t)2 * 32 * 8 * HD * sizeof(float);  // 512 KiB
  hipMemsetAsync((char*)d_ws + flags_off, 0, 32 * 32 * sizeof(unsigned), stream);

  egru_persistent<<<dim3(256), dim3(256), 0, stream>>>(
      xg, h1i, h2i, W1, b1, W2, b2, W3, b3, W4, b4, out, ws);
}

// Round 5
// 3752.988 us; speedup vs baseline: 6.1475x; 1.0325x over previous
//
#include <hip/hip_runtime.h>

#define NT 512   // timesteps
#define FB 128   // feature bins
#define HD 256   // L1 == L2 hidden
#define NC 10

typedef __attribute__((ext_vector_type(8))) short bf16x8;
typedef __attribute__((ext_vector_type(4))) float f32x4;

static __device__ __forceinline__ short f2bf(float f){
  union { float f; unsigned u; } v; v.f = f;
  return (short)((v.u + 0x7fffu + ((v.u >> 16) & 1u)) >> 16);  // RNE
}
static __device__ __forceinline__ float bf2f(short h){
  union { unsigned u; float f; } v; v.u = ((unsigned)(unsigned short)h) << 16;
  return v.f;
}
static __device__ __forceinline__ float quantw(float w){
  return fminf(fmaxf(rintf(w * 8.0f) * 0.125f, -1.0f), 1.0f);  // 4-bit fixed point, exact in bf16
}
static __device__ __forceinline__ bf16x8 loadqw8(const float* __restrict__ p){
  bf16x8 v;
#pragma unroll
  for (int j = 0; j < 8; ++j) v[j] = f2bf(quantw(p[j]));
  return v;
}
// split 8 floats into hi bf16 + lo bf16 (residual)
static __device__ __forceinline__ void split8(f32x4 a, f32x4 b, bf16x8& hi, bf16x8& lo){
  float v0[4] = {a[0],a[1],a[2],a[3]}, v1[4] = {b[0],b[1],b[2],b[3]};
#pragma unroll
  for (int j = 0; j < 4; ++j){
    short h = f2bf(v0[j]); hi[j] = h; lo[j] = f2bf(v0[j] - bf2f(h));
  }
#pragma unroll
  for (int j = 0; j < 4; ++j){
    short h = f2bf(v1[j]); hi[4+j] = h; lo[4+j] = f2bf(v1[j] - bf2f(h));
  }
}

// ---- agent-coherent (sc1) messaging: serviced at the memory-side Infinity
// Cache (single coherent slice per address, shared by all XCDs). No L1/L2
// involvement, no DRAM round trip, no cache-maintenance ops.
static __device__ __forceinline__ void st_sc1_x4(float* p, f32x4 v){
  asm volatile("global_store_dwordx4 %0, %1, off sc1" :: "v"(p), "v"(v) : "memory");
}
static __device__ __forceinline__ void ld_sc1_x8(const float* p, f32x4& a, f32x4& b){
  asm volatile("global_load_dwordx4 %0, %2, off sc1\n\t"
               "global_load_dwordx4 %1, %2, off offset:16 sc1\n\t"
               "s_waitcnt vmcnt(0)"
               : "=&v"(a), "=&v"(b) : "v"(p) : "memory");
}
static __device__ __forceinline__ void st_sc1_u32(unsigned* p, unsigned v){
  asm volatile("global_store_dword %0, %1, off sc1" :: "v"(p), "v"(v) : "memory");
}
static __device__ __forceinline__ unsigned ld_sc1_u32(const unsigned* p){
  unsigned v;
  asm volatile("global_load_dword %0, %1, off sc1\n\ts_waitcnt vmcnt(0)"
               : "=v"(v) : "v"(p) : "memory");
  return v;
}

// Persistent kernel, plain launch (256 blocks = 1/CU; co-resident by construction).
// 256 blocks: group gp = bid&31 (8 batch rows), slice sb = bid>>5 (32 h-dims of W1/W2).
// Software-pipelined: head(t-1) + L2's h2-half hide in the exch1 wait;
// L1(t+1) hides in the exch2 wait. Critical path = 2 exchange round-trips + 16 MFMAs.
__global__ __launch_bounds__(256, 1)
void egru_persistent(const float* __restrict__ xg,
                     const float* __restrict__ h1ig, const float* __restrict__ h2ig,
                     const float* __restrict__ W1g, const float* __restrict__ b1g,
                     const float* __restrict__ W2g, const float* __restrict__ b2g,
                     const float* __restrict__ W3g, const float* __restrict__ b3g,
                     const float* __restrict__ W4g, const float* __restrict__ b4g,
                     float* __restrict__ outg, float* __restrict__ wsf)
{
  const int tid = threadIdx.x;
  const int sb  = blockIdx.x >> 5;   // slice 0..7
  const int gp  = blockIdx.x & 31;   // group 0..31
  const int wv  = tid >> 6;          // wave 0..3
  const int ln  = tid & 15;          // MFMA frag: m/n index (lane&15)
  const int lk  = (tid >> 4) & 3;    // MFMA frag: k-subgroup (lane>>4)
  const int rz  = sb * 32;           // this slice's h-dim base
  const int lnl = 8 + (ln & 7);      // row for lo-part B reads

  __shared__ __align__(16) short in1[16*384];   // [row][k]: k<128 = x(t), k>=128 = h1; rows 0-7 hi, 8-15 lo
  __shared__ __align__(16) short in2[16*512];   // k<256 = h1(t), k>=256 = h2; rows 0-7 hi, 8-15 lo
  __shared__ float a_lds[64][17];
  __shared__ float h1own[32][8];                // fp32 master of own slice [dim][row]
  __shared__ float h2own[32][8];
  __shared__ float h3row[128];
  __shared__ float W4L[10*130];
  __shared__ float b1s[64], b2s[64], b3L[128], b4L[10];

  // workspace: h1buf[32][8][256] f32, h2buf[32][8][256] f32, flags[32][32] u32 (pre-zeroed)
  float* h1buf = wsf + (size_t)gp * (8*HD);
  float* h2buf = wsf + (size_t)32*8*HD + (size_t)gp * (8*HD);
  unsigned* flags = reinterpret_cast<unsigned*>(wsf + (size_t)2*32*8*HD) + gp * 32;

  // ---- resident weight fragments (A-operand: lane holds A[m=ln][k=lk*8+j (+32*ks)]) ----
  bf16x8 w1f[12], w2f[16], w3f[2][8];
  {
    const int arow = (wv < 2) ? (rz + wv*16 + ln) : (256 + rz + (wv-2)*16 + ln);
#pragma unroll
    for (int ks = 0; ks < 12; ++ks) w1f[ks] = loadqw8(W1g + arow*384 + ks*32 + lk*8);
#pragma unroll
    for (int ks = 0; ks < 16; ++ks) w2f[ks] = loadqw8(W2g + arow*512 + ks*32 + lk*8);
#pragma unroll
    for (int tl = 0; tl < 2; ++tl)
#pragma unroll
      for (int ks = 0; ks < 8; ++ks)
        w3f[tl][ks] = loadqw8(W3g + (wv*32 + tl*16 + ln)*256 + ks*32 + lk*8);
  }

  if (tid < 64){
    int grow = (tid < 32) ? (rz + tid) : (256 + rz + (tid - 32));
    b1s[tid] = b1g[grow];
    b2s[tid] = b2g[grow];
  }
  if (tid < 128) b3L[tid] = b3g[tid];
  if (tid < 10)  b4L[tid] = b4g[tid];
  for (int i = tid; i < 1280; i += 256)
    W4L[(i >> 7)*130 + (i & 127)] = quantw(W4g[i]);

  const int ur = tid >> 5, uc = tid & 31;   // (batch row, 8-chunk) mapping, 8x32
  {
    bf16x8 hv, lv;
    const float* p1 = h1ig + (size_t)(gp*8 + ur)*HD + uc*8;
    split8(*(const f32x4*)p1, *(const f32x4*)(p1+4), hv, lv);
    *(bf16x8*)((char*)in1 + ur*768       + ((256 + uc*16) ^ ((ur&7)<<4))) = hv;
    *(bf16x8*)((char*)in1 + (ur+8)*768   + ((256 + uc*16) ^ ((ur&7)<<4))) = lv;
    *(bf16x8*)((char*)in2 + ur*1024      + ((      uc*16) ^ ((ur&7)<<4))) = hv;
    *(bf16x8*)((char*)in2 + (ur+8)*1024  + ((      uc*16) ^ ((ur&7)<<4))) = lv;
    const float* p2 = h2ig + (size_t)(gp*8 + ur)*HD + uc*8;
    split8(*(const f32x4*)p2, *(const f32x4*)(p2+4), hv, lv);
    *(bf16x8*)((char*)in2 + ur*1024      + ((512 + uc*16) ^ ((ur&7)<<4))) = hv;
    *(bf16x8*)((char*)in2 + (ur+8)*1024  + ((512 + uc*16) ^ ((ur&7)<<4))) = lv;
    h1own[uc][ur] = h1ig[(size_t)(gp*8+ur)*HD + rz + uc];
    h2own[uc][ur] = h2ig[(size_t)(gp*8+ur)*HD + rz + uc];
  }
  const int xr = tid >> 4, xf = tid & 15;   // x-staging mapping (rows >=8 unused)
  if (xr < 8){
    const float* px = xg + ((size_t)(gp*8 + xr)*NT + 0)*FB + xf*8;
    bf16x8 hv, lv;
    split8(*(const f32x4*)px, *(const f32x4*)(px+4), hv, lv);
    *(bf16x8*)((char*)in1 + xr*768     + ((xf*16) ^ ((xr&7)<<4))) = hv;
    *(bf16x8*)((char*)in1 + (xr+8)*768 + ((xf*16) ^ ((xr&7)<<4))) = lv;
  }
  __syncthreads();

  // ---- prologue: acc1 = L1(0) ----
  f32x4 acc1 = {0.f,0.f,0.f,0.f};
#pragma unroll
  for (int ks = 0; ks < 12; ++ks){
    bf16x8 bhi = *(bf16x8*)((char*)in1 + ln*768  + ((ks*64 + lk*16) ^ ((ln&7)<<4)));
    bf16x8 blo = *(bf16x8*)((char*)in1 + lnl*768 + ((ks*64 + lk*16) ^ ((ln&7)<<4)));
    acc1 = __builtin_amdgcn_mfma_f32_16x16x32_bf16(w1f[ks], bhi, acc1, 0, 0, 0);
    acc1 = __builtin_amdgcn_mfma_f32_16x16x32_bf16(w1f[ks], blo, acc1, 0, 0, 0);
  }

  for (int t = 0; t < NT; ++t){
    // x(t+1) prefetch (plain cached loads; consumed in the A-window)
    f32x4 xa = {0,0,0,0}, xb = {0,0,0,0};
    const bool pf = ((t+1) < NT) && (xr < 8);
    if (pf){
      const float* px = xg + ((size_t)(gp*8 + xr)*NT + (t+1))*FB + xf*8;
      xa = *(const f32x4*)px; xb = *(const f32x4*)(px+4);
    }

    // ---- A1: finish h1(t) from acc1 (computed last iteration / prologue) ----
#pragma unroll
    for (int r4 = 0; r4 < 4; ++r4){
      int jsl = wv*16 + lk*4 + r4;            // C/D: row=(lane>>4)*4+reg, col=lane&15
      a_lds[jsl][ln] = acc1[r4] + b1s[jsl];
    }
    __syncthreads();
    if (tid < 64){
      const int r = tid >> 3, q = tid & 7;    // row, dim-quad
      f32x4 hv;
#pragma unroll
      for (int i = 0; i < 4; ++i){
        int d = q*4 + i;
        float az = a_lds[d][r], ac = a_lds[32 + d][r];
        float z  = 0.5f*(az/(1.0f+fabsf(az)) + 1.0f);
        float cd = ac/(1.0f+fabsf(ac));
        float hn = z*h1own[d][r] + (1.0f - z)*cd;
        h1own[d][r] = hn;
        hv[i] = hn;
      }
      st_sc1_x4(&h1buf[r*HD + rz + q*4], hv);
    }
    asm volatile("s_waitcnt vmcnt(0)" ::: "memory");   // data stores committed
    __syncthreads();
    if (tid == 0) st_sc1_u32(&flags[sb], (unsigned)(t+1));

    // ======== A-window: hidden work while flag1 propagates ========
    if (pf){  // stage x(t+1); x(t) was consumed by L1(t) last iteration
      bf16x8 hv, lv;
      split8(xa, xb, hv, lv);
      *(bf16x8*)((char*)in1 + xr*768     + ((xf*16) ^ ((xr&7)<<4))) = hv;
      *(bf16x8*)((char*)in1 + (xr+8)*768 + ((xf*16) ^ ((xr&7)<<4))) = lv;
    }
    // L2 partial: W2's h2(t-1) half (ks=8..15), independent of h1(t)
    f32x4 acc2 = {0.f,0.f,0.f,0.f};
#pragma unroll
    for (int ks = 8; ks < 16; ++ks){
      bf16x8 bhi = *(bf16x8*)((char*)in2 + ln*1024  + ((ks*64 + lk*16) ^ ((ln&7)<<4)));
      bf16x8 blo = *(bf16x8*)((char*)in2 + lnl*1024 + ((ks*64 + lk*16) ^ ((ln&7)<<4)));
      acc2 = __builtin_amdgcn_mfma_f32_16x16x32_bf16(w2f[ks], bhi, acc2, 0, 0, 0);
      acc2 = __builtin_amdgcn_mfma_f32_16x16x32_bf16(w2f[ks], blo, acc2, 0, 0, 0);
    }
    // head(t-1): L3 + L4 + log_softmax on h2(t-1) (in2 k>=256)
    if (t > 0){
      f32x4 acc3a = {0,0,0,0}, acc3b = {0,0,0,0};
#pragma unroll
      for (int ks = 0; ks < 8; ++ks){
        bf16x8 bhi = *(bf16x8*)((char*)in2 + ln*1024  + ((512 + ks*64 + lk*16) ^ ((ln&7)<<4)));
        bf16x8 blo = *(bf16x8*)((char*)in2 + lnl*1024 + ((512 + ks*64 + lk*16) ^ ((ln&7)<<4)));
        acc3a = __builtin_amdgcn_mfma_f32_16x16x32_bf16(w3f[0][ks], bhi, acc3a, 0, 0, 0);
        acc3a = __builtin_amdgcn_mfma_f32_16x16x32_bf16(w3f[0][ks], blo, acc3a, 0, 0, 0);
        acc3b = __builtin_amdgcn_mfma_f32_16x16x32_bf16(w3f[1][ks], bhi, acc3b, 0, 0, 0);
        acc3b = __builtin_amdgcn_mfma_f32_16x16x32_bf16(w3f[1][ks], blo, acc3b, 0, 0, 0);
      }
      if (ln == sb){
#pragma unroll
        for (int r4 = 0; r4 < 4; ++r4){
          int d0 = wv*32 + lk*4 + r4;
          h3row[d0]      = fmaxf(acc3a[r4] + b3L[d0],      0.0f);
          h3row[d0 + 16] = fmaxf(acc3b[r4] + b3L[d0 + 16], 0.0f);
        }
      }
      __syncthreads();
      if (wv == 0){
        const int lc = tid;
        float y = -INFINITY;
        if (lc < 10){
          float y0 = 0.f, y1 = 0.f, y2 = 0.f, y3 = 0.f;
#pragma unroll 8
          for (int k = 0; k < 128; k += 4){
            y0 += W4L[lc*130 + k    ] * h3row[k    ];
            y1 += W4L[lc*130 + k + 1] * h3row[k + 1];
            y2 += W4L[lc*130 + k + 2] * h3row[k + 2];
            y3 += W4L[lc*130 + k + 3] * h3row[k + 3];
          }
          y = b4L[lc] + ((y0 + y1) + (y2 + y3));
        }
        float mx = y;
#pragma unroll
        for (int off = 1; off < 16; off <<= 1)
          mx = fmaxf(mx, __shfl_xor(mx, off, 16));
        float ex = (lc < 10) ? expf(y - mx) : 0.0f;
        float sm = ex;
#pragma unroll
        for (int off = 1; off < 16; off <<= 1)
          sm += __shfl_xor(sm, off, 16);
        float lse = mx + logf(sm);
        if (lc < 10)
          outg[((size_t)(gp*8 + sb)*NT + (t-1))*NC + lc] = y - lse;
      }
    }
    // ======== end A-window ========

    if (tid < 8)
      while (ld_sc1_u32(&flags[tid]) < (unsigned)(t+1)) {}
    __syncthreads();
    { // read full h1(t) -> split bf16 into in1 (k>=128) and in2 (k<256)
      f32x4 a0, a1;
      ld_sc1_x8(&h1buf[ur*HD + uc*8], a0, a1);
      bf16x8 hv, lv;
      split8(a0, a1, hv, lv);
      *(bf16x8*)((char*)in1 + ur*768      + ((256 + uc*16) ^ ((ur&7)<<4))) = hv;
      *(bf16x8*)((char*)in1 + (ur+8)*768  + ((256 + uc*16) ^ ((ur&7)<<4))) = lv;
      *(bf16x8*)((char*)in2 + ur*1024     + ((      uc*16) ^ ((ur&7)<<4))) = hv;
      *(bf16x8*)((char*)in2 + (ur+8)*1024 + ((      uc*16) ^ ((ur&7)<<4))) = lv;
    }
    __syncthreads();

    // ---- B: L2's h1(t) half (ks=0..7) -> h2(t) ----
#pragma unroll
    for (int ks = 0; ks < 8; ++ks){
      bf16x8 bhi = *(bf16x8*)((char*)in2 + ln*1024  + ((ks*64 + lk*16) ^ ((ln&7)<<4)));
      bf16x8 blo = *(bf16x8*)((char*)in2 + lnl*1024 + ((ks*64 + lk*16) ^ ((ln&7)<<4)));
      acc2 = __builtin_amdgcn_mfma_f32_16x16x32_bf16(w2f[ks], bhi, acc2, 0, 0, 0);
      acc2 = __builtin_amdgcn_mfma_f32_16x16x32_bf16(w2f[ks], blo, acc2, 0, 0, 0);
    }
#pragma unroll
    for (int r4 = 0; r4 < 4; ++r4){
      int jsl = wv*16 + lk*4 + r4;
      a_lds[jsl][ln] = acc2[r4] + b2s[jsl];
    }
    __syncthreads();
    if (tid < 64){
      const int r = tid >> 3, q = tid & 7;
      f32x4 hv;
#pragma unroll
      for (int i = 0; i < 4; ++i){
        int d = q*4 + i;
        float az = a_lds[d][r], ac = a_lds[32 + d][r];
        float z  = 0.5f*(az/(1.0f+fabsf(az)) + 1.0f);
        float cd = ac/(1.0f+fabsf(ac));
        float hn = z*h2own[d][r] + (1.0f - z)*cd;
        h2own[d][r] = hn;
        hv[i] = hn;
      }
      st_sc1_x4(&h2buf[r*HD + rz + q*4], hv);
    }
    asm volatile("s_waitcnt vmcnt(0)" ::: "memory");
    __syncthreads();
    if (tid == 0) st_sc1_u32(&flags[8 + sb], (unsigned)(t+1));

    // ======== B-window: L1(t+1) while flag2 propagates ========
    if (t + 1 < NT){
      f32x4 a1n = {0.f,0.f,0.f,0.f};
#pragma unroll
      for (int ks = 0; ks < 12; ++ks){
        bf16x8 bhi = *(bf16x8*)((char*)in1 + ln*768  + ((ks*64 + lk*16) ^ ((ln&7)<<4)));
        bf16x8 blo = *(bf16x8*)((char*)in1 + lnl*768 + ((ks*64 + lk*16) ^ ((ln&7)<<4)));
        a1n = __builtin_amdgcn_mfma_f32_16x16x32_bf16(w1f[ks], bhi, a1n, 0, 0, 0);
        a1n = __builtin_amdgcn_mfma_f32_16x16x32_bf16(w1f[ks], blo, a1n, 0, 0, 0);
      }
      acc1 = a1n;
    }
    // ======== end B-window ========

    if (tid < 8)
      while (ld_sc1_u32(&flags[8 + tid]) < (unsigned)(t+1)) {}
    __syncthreads();
    { // read full h2(t) -> in2 (k>=256); serves next L2-partial, head(t), L3 epilogue
      f32x4 a0, a1;
      ld_sc1_x8(&h2buf[ur*HD + uc*8], a0, a1);
      bf16x8 hv, lv;
      split8(a0, a1, hv, lv);
      *(bf16x8*)((char*)in2 + ur*1024     + ((512 + uc*16) ^ ((ur&7)<<4))) = hv;
      *(bf16x8*)((char*)in2 + (ur+8)*1024 + ((512 + uc*16) ^ ((ur&7)<<4))) = lv;
    }
    __syncthreads();
  }

  // ---- epilogue: head(NT-1) ----
  {
    f32x4 acc3a = {0,0,0,0}, acc3b = {0,0,0,0};
#pragma unroll
    for (int ks = 0; ks < 8; ++ks){
      bf16x8 bhi = *(bf16x8*)((char*)in2 + ln*1024  + ((512 + ks*64 + lk*16) ^ ((ln&7)<<4)));
      bf16x8 blo = *(bf16x8*)((char*)in2 + lnl*1024 + ((512 + ks*64 + lk*16) ^ ((ln&7)<<4)));
      acc3a = __builtin_amdgcn_mfma_f32_16x16x32_bf16(w3f[0][ks], bhi, acc3a, 0, 0, 0);
      acc3a = __builtin_amdgcn_mfma_f32_16x16x32_bf16(w3f[0][ks], blo, acc3a, 0, 0, 0);
      acc3b = __builtin_amdgcn_mfma_f32_16x16x32_bf16(w3f[1][ks], bhi, acc3b, 0, 0, 0);
      acc3b = __builtin_amdgcn_mfma_f32_16x16x32_bf16(w3f[1][ks], blo, acc3b, 0, 0, 0);
    }
    if (ln == sb){
#pragma unroll
      for (int r4 = 0; r4 < 4; ++r4){
        int d0 = wv*32 + lk*4 + r4;
        h3row[d0]      = fmaxf(acc3a[r4] + b3L[d0],      0.0f);
        h3row[d0 + 16] = fmaxf(acc3b[r4] + b3L[d0 + 16], 0.0f);
      }
    }
    __syncthreads();
    if (wv == 0){
      const int lc = tid;
      float y = -INFINITY;
      if (lc < 10){
        float y0 = 0.f, y1 = 0.f, y2 = 0.f, y3 = 0.f;
#pragma unroll 8
        for (int k = 0; k < 128; k += 4){
          y0 += W4L[lc*130 + k    ] * h3row[k    ];
          y1 += W4L[lc*130 + k + 1] * h3row[k + 1];
          y2 += W4L[lc*130 + k + 2] * h3row[k + 2];
          y3 += W4L[lc*130 + k + 3] * h3row[k + 3];
        }
        y = b4L[lc] + ((y0 + y1) + (y2 + y3));
      }
      float mx = y;
#pragma unroll
      for (int off = 1; off < 16; off <<= 1)
        mx = fmaxf(mx, __shfl_xor(mx, off, 16));
      float ex = (lc < 10) ? expf(y - mx) : 0.0f;
      float sm = ex;
#pragma unroll
      for (int off = 1; off < 16; off <<= 1)
        sm += __shfl_xor(sm, off, 16);
      float lse = mx + logf(sm);
      if (lc < 10)
        outg[((size_t)(gp*8 + sb)*NT + (NT-1))*NC + lc] = y - lse;
    }
  }
}

extern "C" void kernel_launch(void* const* d_in, const int* in_sizes, int n_in,
                              void* d_out, int out_size, void* d_ws, size_t ws_size,
                              hipStream_t stream) {
  const float* xg  = (const float*)d_in[0];
  const float* h1i = (const float*)d_in[1];
  const float* h2i = (const float*)d_in[2];
  const float* W1  = (const float*)d_in[3];
  const float* b1  = (const float*)d_in[4];
  const float* W2  = (const float*)d_in[5];
  const float* b2  = (const float*)d_in[6];
  const float* W3  = (const float*)d_in[7];
  const float* b3  = (const float*)d_in[8];
  const float* W4  = (const float*)d_in[9];
  const float* b4  = (const float*)d_in[10];
  float* out = (float*)d_out;
  float* ws  = (float*)d_ws;

  // zero the flag words (stream-ordered, completes before the kernel starts)
  const size_t flags_off = (size_t)2 * 32 * 8 * HD * sizeof(float);  // 512 KiB
  hipMemsetAsync((char*)d_ws + flags_off, 0, 32 * 32 * sizeof(unsigned), stream);

  egru_persistent<<<dim3(256), dim3(256), 0, stream>>>(
      xg, h1i, h2i, W1, b1, W2, b2, W3, b3, W4, b4, out, ws);
}